// Round 7
// baseline (864.210 us; speedup 1.0000x reference)
//
#include <hip/hip_runtime.h>
#include <math.h>

#define NEG_SLOPE 0.2f

typedef _Float16 half8 __attribute__((ext_vector_type(8)));
typedef float float4v __attribute__((ext_vector_type(4)));
typedef float float2v __attribute__((ext_vector_type(2)));

__device__ __forceinline__ float lrelu(float x) { return x > 0.f ? x : NEG_SLOPE * x; }

__device__ __forceinline__ unsigned char f32_to_fp8(float a) {
  int v = __builtin_amdgcn_cvt_pk_fp8_f32(a, 0.f, 0, false);
  return (unsigned char)(v & 0xff);
}

__device__ __forceinline__ void acc_fp8x8(float* acc, uint2 d, float ez) {
  float2v c0 = __builtin_amdgcn_cvt_pk_f32_fp8((int)d.x, false);
  float2v c1 = __builtin_amdgcn_cvt_pk_f32_fp8((int)d.x, true);
  float2v c2 = __builtin_amdgcn_cvt_pk_f32_fp8((int)d.y, false);
  float2v c3 = __builtin_amdgcn_cvt_pk_f32_fp8((int)d.y, true);
  acc[0] += ez * c0.x; acc[1] += ez * c0.y;
  acc[2] += ez * c1.x; acc[3] += ez * c1.y;
  acc[4] += ez * c2.x; acc[5] += ez * c2.y;
  acc[6] += ez * c3.x; acc[7] += ez * c3.y;
}

__device__ __forceinline__ void acc_fp8x16(float* acc, uint4 d, float ez) {
  acc_fp8x8(acc, make_uint2(d.x, d.y), ez);
  acc_fp8x8(acc + 8, make_uint2(d.z, d.w), ez);
}

// ---------------- CSR build ----------------

__global__ void k_hist(const int* __restrict__ dst, int* __restrict__ cnt, int E) {
  int i = blockIdx.x * blockDim.x + threadIdx.x;
  if (i < E) atomicAdd(&cnt[dst[i]], 1);
}

__global__ __launch_bounds__(256) void k_offsets(const int* __restrict__ cnt,
                                                 int* __restrict__ row_start,
                                                 int* __restrict__ gcount, int N) {
  __shared__ int s[256];
  __shared__ int base;
  int tid = threadIdx.x;
  int i = blockIdx.x * 256 + tid;
  int c = (i < N) ? cnt[i] : 0;
  s[tid] = c;
  __syncthreads();
  for (int off = 1; off < 256; off <<= 1) {
    int v = 0;
    if (tid >= off) v = s[tid - off];
    __syncthreads();
    if (tid >= off) s[tid] += v;
    __syncthreads();
  }
  if (tid == 255) base = atomicAdd(gcount, s[255]);
  __syncthreads();
  if (i < N) row_start[i] = base + s[tid] - c;
}

__global__ void k_scatter(const int* __restrict__ src, const int* __restrict__ dst,
                          const int* __restrict__ row_start, int* __restrict__ fill,
                          int* __restrict__ srcs, int* __restrict__ dsts, int E) {
  int i = blockIdx.x * blockDim.x + threadIdx.x;
  if (i < E) {
    int d = dst[i];
    int p = row_start[d] + atomicAdd(&fill[d], 1);
    srcs[p] = src[i];
    dsts[p] = d;
  }
}

// ---------------- fused prep: wlr0/1/2 + Wt0/1/2 ----------------
__device__ __forceinline__ void wlr_one(const float* Ws, const float* Wd,
                                        const float* al, const float* ar,
                                        float* wlr, int K, int Dh, int i) {
  int M = 4 * Dh;
  int k = i >> 2, h = i & 3;
  float sl = 0.f, sr = 0.f;
  for (int d = 0; d < Dh; d++) {
    sl += Ws[(size_t)k * M + h * Dh + d] * al[h * Dh + d];
    sr += Wd[(size_t)k * M + h * Dh + d] * ar[h * Dh + d];
  }
  wlr[k * 8 + h] = sl;
  wlr[k * 8 + 4 + h] = sr;
}

__global__ __launch_bounds__(256) void k_prep(
    const float* __restrict__ W0s, const float* __restrict__ W0d,
    const float* __restrict__ a0l, const float* __restrict__ a0r,
    const float* __restrict__ W1s, const float* __restrict__ W1d,
    const float* __restrict__ a1l, const float* __restrict__ a1r,
    const float* __restrict__ W2s, const float* __restrict__ W2d,
    const float* __restrict__ a2l, const float* __restrict__ a2r,
    float* __restrict__ wlr0, float* __restrict__ wlr1, float* __restrict__ wlr2,
    _Float16* __restrict__ Wt0, _Float16* __restrict__ Wt1, _Float16* __restrict__ Wt2) {
  int i = blockIdx.x * 256 + threadIdx.x;
  if (i < 1024) {
    wlr_one(W0s, W0d, a0l, a0r, wlr0, 256, 32, i);
  } else if (i < 1536) {
    wlr_one(W1s, W1d, a1l, a1r, wlr1, 128, 32, i - 1024);
  } else if (i < 2048) {
    wlr_one(W2s, W2d, a2l, a2r, wlr2, 128, 47, i - 1536);
  } else if (i < 2048 + 32768) {
    int j = i - 2048;                 // Wt0[128][256]
    int m = j >> 8, k = j & 255;
    Wt0[j] = (_Float16)W0s[(size_t)k * 128 + m];
  } else if (i < 2048 + 32768 + 16384) {
    int j = i - (2048 + 32768);       // Wt1[128][128]
    int m = j >> 7, k = j & 127;
    Wt1[j] = (_Float16)W1s[(size_t)k * 128 + m];
  } else if (i < 2048 + 32768 + 16384 + 24576) {
    int j = i - (2048 + 32768 + 16384);  // Wt2[192][128], head-padded rows 48*h+c
    int r = j >> 7, k = j & 127;
    int h = r / 48, c = r % 48;
    float v = (c < 47) ? W2s[(size_t)k * 188 + 47 * h + c] : 0.f;
    Wt2[j] = (_Float16)v;
  }
}

// ---------------- el/er: H @ wlr  ([N,K] x [K,8]) ----------------
template <typename T>
__global__ __launch_bounds__(256) void k_eler(const T* __restrict__ H,
                                              const float* __restrict__ wlr,
                                              float* __restrict__ el, float* __restrict__ er,
                                              int N, int K) {
  __shared__ float ws[2048];
  for (int i = threadIdx.x; i < K * 8; i += 256) ws[i] = wlr[i];
  __syncthreads();
  int lane = threadIdx.x & 63;
  int node = blockIdx.x * 4 + (threadIdx.x >> 6);
  if (node >= N) return;
  float p[8] = {0, 0, 0, 0, 0, 0, 0, 0};
  for (int k = lane; k < K; k += 64) {
    float hv = (float)H[(size_t)node * K + k];
#pragma unroll
    for (int j = 0; j < 8; j++) p[j] += hv * ws[k * 8 + j];
  }
#pragma unroll
  for (int j = 0; j < 8; j++) {
#pragma unroll
    for (int m = 1; m < 64; m <<= 1) p[j] += __shfl_xor(p[j], m);
  }
  if (lane == 0) {
    *(float4*)&el[(size_t)node * 4] = make_float4(p[0], p[1], p[2], p[3]);
    *(float4*)&er[(size_t)node * 4] = make_float4(p[4], p[5], p[6], p[7]);
  }
}

// ---------------- edge-parallel ez: Ez[p] = exp(lrelu(el[src]+er[dst])) ----------------
__global__ __launch_bounds__(256) void k_ez(const int* __restrict__ srcs,
                                            const int* __restrict__ dsts,
                                            const float* __restrict__ el,
                                            const float* __restrict__ er,
                                            float* __restrict__ Ez, int E) {
  int p = blockIdx.x * 256 + threadIdx.x;
  if (p < E) {
    int u = srcs[p], d = dsts[p];
    float4 a = *(const float4*)&el[(size_t)u * 4];
    float4 b = *(const float4*)&er[(size_t)d * 4];
    float4 z;
    z.x = __expf(lrelu(a.x + b.x));
    z.y = __expf(lrelu(a.y + b.y));
    z.z = __expf(lrelu(a.z + b.z));
    z.w = __expf(lrelu(a.w + b.w));
    *(float4*)&Ez[(size_t)p * 4] = z;
  }
}

// ---------------- MFMA fp16 GEMM; C stored fp8 ----------------
template <int BN, typename AT>
__global__ __launch_bounds__(256) void k_gemm_mfma(const AT* __restrict__ A,
                                                   const _Float16* __restrict__ Bt,
                                                   unsigned char* __restrict__ C, int N, int K) {
  constexpr int NT = BN / 64;                 // n-tiles per wave (2 or 3)
  constexpr int ASZ = 4 * 64 * 8;             // 2048 fp16
  constexpr int BSZ = (BN / 16) * 64 * 8;     // 4096 or 6144 fp16
  constexpr int SSZ = ASZ + BSZ;              // bytes*2 >= 64*BN for fp8 retile
  __shared__ __align__(16) _Float16 smem[SSZ];
  _Float16* As = smem;
  _Float16* Bs = smem + ASZ;

  const int tid = threadIdx.x;
  const int lane = tid & 63;
  const int w = tid >> 6;
  const int row0 = blockIdx.x * 64;

  float4v acc[4][NT];
#pragma unroll
  for (int i = 0; i < 4; i++)
#pragma unroll
    for (int j = 0; j < NT; j++) acc[i][j] = (float4v){0.f, 0.f, 0.f, 0.f};

  const int ar_ = tid >> 2, aq = tid & 3;
  for (int k0 = 0; k0 < K; k0 += 32) {
    {
      int gr = row0 + ar_;
      half8 v;
      if (gr < N) {
        if constexpr (sizeof(AT) == 4) {
          const float4* pp = (const float4*)&A[(size_t)gr * K + k0 + aq * 8];
          float4 u0 = pp[0], u1 = pp[1];
          v[0] = (_Float16)u0.x; v[1] = (_Float16)u0.y; v[2] = (_Float16)u0.z; v[3] = (_Float16)u0.w;
          v[4] = (_Float16)u1.x; v[5] = (_Float16)u1.y; v[6] = (_Float16)u1.z; v[7] = (_Float16)u1.w;
        } else {
          v = *(const half8*)&A[(size_t)gr * K + k0 + aq * 8];
        }
      } else {
#pragma unroll
        for (int j = 0; j < 8; j++) v[j] = (_Float16)0.f;
      }
      *(half8*)&As[(size_t)(((ar_ >> 4) * 64) + (ar_ & 15) + 16 * aq) * 8] = v;
    }
#pragma unroll
    for (int i = 0; i < NT; i++) {
      int idx = tid + i * 256;
      int n = idx >> 2, q = idx & 3;
      half8 v = *(const half8*)&Bt[(size_t)n * K + k0 + q * 8];
      *(half8*)&Bs[(size_t)((n >> 4) * 64 + (n & 15) + 16 * q) * 8] = v;
    }
    __syncthreads();
    half8 af[4];
#pragma unroll
    for (int mt = 0; mt < 4; mt++) af[mt] = *(half8*)&As[(size_t)(mt * 64 + lane) * 8];
#pragma unroll
    for (int nt = 0; nt < NT; nt++) {
      half8 bf = *(half8*)&Bs[(size_t)((w * NT + nt) * 64 + lane) * 8];
#pragma unroll
      for (int mt = 0; mt < 4; mt++)
        acc[mt][nt] = __builtin_amdgcn_mfma_f32_16x16x32_f16(af[mt], bf, acc[mt][nt], 0, 0, 0);
    }
    __syncthreads();
  }

  unsigned char* cs = (unsigned char*)smem;
  const int quad = lane >> 4;
#pragma unroll
  for (int mt = 0; mt < 4; mt++)
#pragma unroll
    for (int nt = 0; nt < NT; nt++)
#pragma unroll
      for (int reg = 0; reg < 4; reg++) {
        int r = mt * 16 + quad * 4 + reg;
        int cc = (w * NT + nt) * 16 + (lane & 15);
        cs[r * BN + cc] = f32_to_fp8(acc[mt][nt][reg]);
      }
  __syncthreads();
  constexpr int PER = (64 * BN) / (256 * 16);
  const uint4* s4 = (const uint4*)cs;
#pragma unroll
  for (int i = 0; i < PER; i++) {
    int idx = tid + i * 256;
    int r = idx / (BN / 16), c16 = idx % (BN / 16);
    int gr = row0 + r;
    if (gr < N) *(uint4*)&C[(size_t)gr * BN + c16 * 16] = s4[idx];
  }
}

// ---------------- aggregation, layers 0/1 (F fp8, stride 128) ----------------
// Wave per node; 4 groups of 16 lanes, group = one edge at a time; lane owns
// 8 feats (8B load). srcs broadcast + Ez streamed; next (u,ez) prefetched.
__global__ __launch_bounds__(256) void k_agg_mid(
    const unsigned char* __restrict__ F, const float* __restrict__ Ez,
    const int* __restrict__ row_start, const int* __restrict__ cnt,
    const int* __restrict__ srcs, const float* __restrict__ bias,
    _Float16* __restrict__ hout, int N) {
  int lane = threadIdx.x & 63;
  int v = blockIdx.x * 4 + (threadIdx.x >> 6);
  if (v >= N) return;
  int start = row_start[v], deg = cnt[v];
  int end = start + deg;
  const int g = lane >> 4;
  const int fl = lane & 15;
  const int h = fl >> 2;
  float acc[8] = {0, 0, 0, 0, 0, 0, 0, 0};
  float lsum = 0.f;

  int pg = start + g;
  int u = 0;
  float ezv = 0.f;
  if (pg < end) {
    u = srcs[pg];
    ezv = Ez[(size_t)pg * 4 + h];
  }
  while (pg < end) {
    int pn = pg + 4;
    int u2 = 0;
    float ez2 = 0.f;
    if (pn < end) {
      u2 = srcs[pn];
      ez2 = Ez[(size_t)pn * 4 + h];
    }
    uint2 d = *(const uint2*)&F[(size_t)u * 128 + 8 * fl];
    acc_fp8x8(acc, d, ezv);
    lsum += ezv;
    u = u2; ezv = ez2; pg = pn;
  }
#pragma unroll
  for (int j = 0; j < 8; j++) {
    acc[j] += __shfl_xor(acc[j], 16);
    acc[j] += __shfl_xor(acc[j], 32);
  }
  lsum += __shfl_xor(lsum, 16);
  lsum += __shfl_xor(lsum, 32);
  if (g == 0) {
    float inv = (deg > 0) ? 1.f / lsum : 0.f;
    const float4* bp = (const float4*)&bias[8 * fl];
    float4 b0v = bp[0], b1v = bp[1];
    float bb[8] = {b0v.x, b0v.y, b0v.z, b0v.w, b1v.x, b1v.y, b1v.z, b1v.w};
    half8 o;
#pragma unroll
    for (int j = 0; j < 8; j++) o[j] = (_Float16)fmaxf(fmaf(acc[j], inv, bb[j]), 0.f);
    *(half8*)&hout[(size_t)v * 128 + 8 * fl] = o;
  }
}

// ---------------- aggregation, layer 2 (F fp8, head-padded 4x48, stride 192) ----------------
// 4 groups of 16 lanes (12 active): lane owns 16 feats (16B load); head = fl/3.
__global__ __launch_bounds__(256) void k_agg_final(
    const unsigned char* __restrict__ F, const float* __restrict__ Ez,
    const int* __restrict__ row_start, const int* __restrict__ cnt,
    const int* __restrict__ srcs, const float* __restrict__ b2,
    float* __restrict__ out, int N) {
  __shared__ float red[4][192];
  int lane = threadIdx.x & 63;
  int w = threadIdx.x >> 6;
  int v = blockIdx.x * 4 + w;
  if (v >= N) return;
  int start = row_start[v], deg = cnt[v];
  int end = start + deg;
  const int g = lane >> 4;
  const int fl = lane & 15;
  const bool act = fl < 12;
  const int h = fl / 3;  // valid for fl<12
  float acc[16];
#pragma unroll
  for (int j = 0; j < 16; j++) acc[j] = 0.f;
  float lsum = 0.f;

  if (act) {
    int pg = start + g;
    int u = 0;
    float ezv = 0.f;
    if (pg < end) {
      u = srcs[pg];
      ezv = Ez[(size_t)pg * 4 + h];
    }
    while (pg < end) {
      int pn = pg + 4;
      int u2 = 0;
      float ez2 = 0.f;
      if (pn < end) {
        u2 = srcs[pn];
        ez2 = Ez[(size_t)pn * 4 + h];
      }
      uint4 d = *(const uint4*)&F[(size_t)u * 192 + 16 * fl];
      acc_fp8x16(acc, d, ezv);
      lsum += ezv;
      u = u2; ezv = ez2; pg = pn;
    }
  }
#pragma unroll
  for (int j = 0; j < 16; j++) {
    acc[j] += __shfl_xor(acc[j], 16);
    acc[j] += __shfl_xor(acc[j], 32);
  }
  lsum += __shfl_xor(lsum, 16);
  lsum += __shfl_xor(lsum, 32);
  if (g == 0 && act) {
    float inv = (deg > 0) ? 1.f / lsum : 0.f;
    int c0 = 16 * (fl % 3);
#pragma unroll
    for (int j = 0; j < 16; j++) {
      int c = c0 + j;
      float bv = (c < 47) ? b2[47 * h + c] : 0.f;
      red[w][16 * fl + j] = fmaf(acc[j], inv, bv);
    }
  }
  __syncthreads();
  float gg = -INFINITY;
  if (lane < 47)
    gg = 0.25f * (red[w][lane] + red[w][lane + 48] + red[w][lane + 96] + red[w][lane + 144]);
  float gm = gg;
#pragma unroll
  for (int msk = 1; msk < 64; msk <<= 1) gm = fmaxf(gm, __shfl_xor(gm, msk));
  float ex = (lane < 47) ? __expf(gg - gm) : 0.f;
  float s = ex;
#pragma unroll
  for (int msk = 1; msk < 64; msk <<= 1) s += __shfl_xor(s, msk);
  if (lane < 47) out[(size_t)v * 47 + lane] = gg - gm - __logf(s);
}

// ---------------- launch ----------------
extern "C" void kernel_launch(void* const* d_in, const int* in_sizes, int n_in,
                              void* d_out, int out_size, void* d_ws, size_t ws_size,
                              hipStream_t stream) {
  const float* x = (const float*)d_in[0];
  const int* src = (const int*)d_in[1];
  const int* dst = (const int*)d_in[2];
  const float* W0s = (const float*)d_in[3];
  const float* W0d = (const float*)d_in[4];
  const float* a0l = (const float*)d_in[5];
  const float* a0r = (const float*)d_in[6];
  const float* b0 = (const float*)d_in[7];
  const float* W1s = (const float*)d_in[8];
  const float* W1d = (const float*)d_in[9];
  const float* a1l = (const float*)d_in[10];
  const float* a1r = (const float*)d_in[11];
  const float* b1 = (const float*)d_in[12];
  const float* W2s = (const float*)d_in[13];
  const float* W2d = (const float*)d_in[14];
  const float* a2l = (const float*)d_in[15];
  const float* a2r = (const float*)d_in[16];
  const float* b2 = (const float*)d_in[17];
  float* out = (float*)d_out;

  const int N = in_sizes[0] / 256;  // 100000
  const int E = in_sizes[1];        // 1600000

  char* w = (char*)d_ws;
  size_t off = 0;
  auto alloc = [&](size_t bytes) -> void* {
    void* p = w + off;
    off += (bytes + 255) & ~(size_t)255;
    return p;
  };
  int* gcount = (int*)alloc(4);
  int* cnt = (int*)alloc((size_t)N * 4);
  int* fill = (int*)alloc((size_t)N * 4);
  size_t zbytes = off;  // zero gcount+cnt+fill
  int* row_start = (int*)alloc((size_t)N * 4);
  int* srcs = (int*)alloc((size_t)E * 4);
  int* dsts = (int*)alloc((size_t)E * 4);
  float* Ez = (float*)alloc((size_t)E * 4 * 4);
  float* wlr0 = (float*)alloc(256 * 8 * 4);
  float* wlr1 = (float*)alloc(128 * 8 * 4);
  float* wlr2 = (float*)alloc(128 * 8 * 4);
  _Float16* Wt0 = (_Float16*)alloc(128 * 256 * 2);
  _Float16* Wt1 = (_Float16*)alloc(128 * 128 * 2);
  _Float16* Wt2 = (_Float16*)alloc(192 * 128 * 2);
  float* el = (float*)alloc((size_t)N * 4 * 4);
  float* er = (float*)alloc((size_t)N * 4 * 4);
  unsigned char* F = (unsigned char*)alloc((size_t)N * 192);
  _Float16* Ha = (_Float16*)alloc((size_t)N * 128 * 2);
  _Float16* Hc = (_Float16*)alloc((size_t)N * 128 * 2);
  (void)ws_size;

  hipMemsetAsync(d_ws, 0, zbytes, stream);
  k_hist<<<(E + 255) / 256, 256, 0, stream>>>(dst, cnt, E);
  k_offsets<<<(N + 255) / 256, 256, 0, stream>>>(cnt, row_start, gcount, N);
  k_scatter<<<(E + 255) / 256, 256, 0, stream>>>(src, dst, row_start, fill, srcs, dsts, E);
  k_prep<<<(75776 + 255) / 256, 256, 0, stream>>>(W0s, W0d, a0l, a0r, W1s, W1d, a1l, a1r,
                                                  W2s, W2d, a2l, a2r, wlr0, wlr1, wlr2,
                                                  Wt0, Wt1, Wt2);

  int gemm_grid = (N + 63) / 64;
  int node_grid = (N + 3) / 4;
  int edge_grid = (E + 255) / 256;

  // layer 0: K=256, fp32 A (x)
  k_gemm_mfma<128, float><<<gemm_grid, 256, 0, stream>>>(x, Wt0, F, N, 256);
  k_eler<float><<<node_grid, 256, 0, stream>>>(x, wlr0, el, er, N, 256);
  k_ez<<<edge_grid, 256, 0, stream>>>(srcs, dsts, el, er, Ez, E);
  k_agg_mid<<<node_grid, 256, 0, stream>>>(F, Ez, row_start, cnt, srcs, b0, Ha, N);

  // layer 1: K=128, fp16 A
  k_gemm_mfma<128, _Float16><<<gemm_grid, 256, 0, stream>>>(Ha, Wt1, F, N, 128);
  k_eler<_Float16><<<node_grid, 256, 0, stream>>>(Ha, wlr1, el, er, N, 128);
  k_ez<<<edge_grid, 256, 0, stream>>>(srcs, dsts, el, er, Ez, E);
  k_agg_mid<<<node_grid, 256, 0, stream>>>(F, Ez, row_start, cnt, srcs, b1, Hc, N);

  // layer 2: K=128, M=192 head-padded (4 x 48, col 47 of each head zero)
  k_gemm_mfma<192, _Float16><<<gemm_grid, 256, 0, stream>>>(Hc, Wt2, F, N, 128);
  k_eler<_Float16><<<node_grid, 256, 0, stream>>>(Hc, wlr2, el, er, N, 128);
  k_ez<<<edge_grid, 256, 0, stream>>>(srcs, dsts, el, er, Ez, E);
  k_agg_final<<<node_grid, 256, 0, stream>>>(F, Ez, row_start, cnt, srcs, b2, out, N);
}